// Round 13
// baseline (377.353 us; speedup 1.0000x reference)
//
#include <hip/hip_runtime.h>
#include <hip/hip_fp16.h>
#include <hip/hip_fp8.h>

// GCN: z1 = relu(Agg(x@W1)+b1); out = ((P·Â·z1)@W2 + b2)@Wfc + bfc
//   (pooling commuted before W2; P·Â·z1 pooled row-wise over dst).
// ONE CSR (by dst) serves both layers. Intermediates h1/z1 FP8 e4m3 (HW
// cvt_pk path, round-12). Round-12 lesson: agg is miss-LATENCY bound with
// ~2-4 effective outstanding gathers/wave (bytes-halving and request-halving
// both null) — fix is a real software pipeline: 8 edge-slots/wave (8 lanes x
// uint4 = full 128B row), csr descriptors 3 batches ahead, H rows 1 batch
// ahead, static register rotation. Build: 1 atomic/edge (~67us floor).

constexpr int FDIM = 128;

typedef __attribute__((ext_vector_type(8))) short short8v;
typedef __attribute__((ext_vector_type(4))) float f32x4;
typedef __attribute__((ext_vector_type(2))) float f32x2;

__device__ __forceinline__ ushort f2bf(float f) {
    uint u = __float_as_uint(f);
    return (ushort)((u + 0x7fffu + ((u >> 16) & 1u)) >> 16);
}

#if __has_builtin(__builtin_amdgcn_cvt_pk_f32_fp8) && __has_builtin(__builtin_amdgcn_cvt_pk_fp8_f32)
#define FP8_HW 1
#else
#define FP8_HW 0
#endif

__device__ __forceinline__ void fp8x16_dec(uint4 v, float* f) {
#if FP8_HW
    f32x2 a = __builtin_amdgcn_cvt_pk_f32_fp8(v.x, false);
    f32x2 b = __builtin_amdgcn_cvt_pk_f32_fp8(v.x, true);
    f32x2 c = __builtin_amdgcn_cvt_pk_f32_fp8(v.y, false);
    f32x2 d = __builtin_amdgcn_cvt_pk_f32_fp8(v.y, true);
    f[0] = a[0]; f[1] = a[1]; f[2] = b[0]; f[3] = b[1];
    f[4] = c[0]; f[5] = c[1]; f[6] = d[0]; f[7] = d[1];
    a = __builtin_amdgcn_cvt_pk_f32_fp8(v.z, false);
    b = __builtin_amdgcn_cvt_pk_f32_fp8(v.z, true);
    c = __builtin_amdgcn_cvt_pk_f32_fp8(v.w, false);
    d = __builtin_amdgcn_cvt_pk_f32_fp8(v.w, true);
    f[8] = a[0]; f[9] = a[1]; f[10] = b[0]; f[11] = b[1];
    f[12] = c[0]; f[13] = c[1]; f[14] = d[0]; f[15] = d[1];
#else
    for (int k = 0; k < 4; k++) {
        uint w = (&v.x)[k];
        __half2_raw h;
        h = __hip_cvt_fp8x2_to_halfraw2((__hip_fp8x2_storage_t)(w & 0xffffu), __HIP_E4M3);
        float2 a = __half22float2(*(__half2*)&h);
        f[k * 4 + 0] = a.x; f[k * 4 + 1] = a.y;
        h = __hip_cvt_fp8x2_to_halfraw2((__hip_fp8x2_storage_t)(w >> 16), __HIP_E4M3);
        a = __half22float2(*(__half2*)&h);
        f[k * 4 + 2] = a.x; f[k * 4 + 3] = a.y;
    }
#endif
}
__device__ __forceinline__ uint4 fp8x16_enc(const float* f) {
#if FP8_HW
    int w0 = 0, w1 = 0, w2 = 0, w3 = 0;
    w0 = __builtin_amdgcn_cvt_pk_fp8_f32(f[0], f[1], w0, false);
    w0 = __builtin_amdgcn_cvt_pk_fp8_f32(f[2], f[3], w0, true);
    w1 = __builtin_amdgcn_cvt_pk_fp8_f32(f[4], f[5], w1, false);
    w1 = __builtin_amdgcn_cvt_pk_fp8_f32(f[6], f[7], w1, true);
    w2 = __builtin_amdgcn_cvt_pk_fp8_f32(f[8], f[9], w2, false);
    w2 = __builtin_amdgcn_cvt_pk_fp8_f32(f[10], f[11], w2, true);
    w3 = __builtin_amdgcn_cvt_pk_fp8_f32(f[12], f[13], w3, false);
    w3 = __builtin_amdgcn_cvt_pk_fp8_f32(f[14], f[15], w3, true);
    return make_uint4((uint)w0, (uint)w1, (uint)w2, (uint)w3);
#else
    uint w[4];
    for (int k = 0; k < 4; k++) {
        uint p0 = __hip_cvt_float2_to_fp8x2(make_float2(f[k*4+0], f[k*4+1]), __HIP_SATFINITE, __HIP_E4M3);
        uint p1 = __hip_cvt_float2_to_fp8x2(make_float2(f[k*4+2], f[k*4+3]), __HIP_SATFINITE, __HIP_E4M3);
        w[k] = p0 | (p1 << 16);
    }
    return make_uint4(w[0], w[1], w[2], w[3]);
#endif
}
__device__ __forceinline__ uchar fp8_enc1(float f) {
#if FP8_HW
    return (uchar)((uint)__builtin_amdgcn_cvt_pk_fp8_f32(f, f, 0, false) & 0xffu);
#else
    return (uchar)__hip_cvt_float_to_fp8(f, __HIP_SATFINITE, __HIP_E4M3);
#endif
}

// ---------------- init: zero histogram + psum ----------------
__global__ __launch_bounds__(256) void k_init(unsigned long long* packed,
                                              float* psum, int NN, int PS) {
    int i = blockIdx.x * 256 + threadIdx.x;
    if (i < NN) packed[i] = 0ULL;
    if (i < PS) psum[i] = 0.0f;
}

// ---------------- histogram + CSR position (single atomic/edge) --------------
__global__ __launch_bounds__(256) void k_hist(const int* __restrict__ dst,
                                              const float* __restrict__ ew,
                                              unsigned long long* __restrict__ packed,
                                              ushort* __restrict__ aux, int E) {
    int e = blockIdx.x * 256 + threadIdx.x;
    if (e < E) {
        int d = dst[e];
        uint fix = __float2uint_rn(ew[e] * 16777216.0f);   // 2^24 fixed point
        unsigned long long old =
            atomicAdd(&packed[d], (1ULL << 32) | (unsigned long long)fix);
        aux[e] = (ushort)(old >> 32);                      // slot in dst bucket
    }
}

// ---------------- merge: packed -> cnt, dinv ----------------
__global__ __launch_bounds__(256) void k_merge(const unsigned long long* __restrict__ packed,
                                               int* __restrict__ cnt,
                                               float* __restrict__ dinv, int NN) {
    int n = blockIdx.x * 256 + threadIdx.x;
    if (n >= NN) return;
    unsigned long long v = packed[n];
    cnt[n] = (int)(v >> 32);
    float deg = 1.0f + (float)(v & 0xffffffffULL) * 5.9604644775390625e-8f;  // 2^-24
    dinv[n] = rsqrtf(deg);
}

// ---------------- exclusive scan (3-kernel, chunk=1024) ----------------
__global__ __launch_bounds__(256) void k_bsum(const int* __restrict__ cnt, int* bsum, int NN) {
    __shared__ int lds[256];
    int b = blockIdx.x, t = threadIdx.x;
    int base = b * 1024;
    int s = 0;
#pragma unroll
    for (int j = 0; j < 4; j++) {
        int i = base + j * 256 + t;
        if (i < NN) s += cnt[i];
    }
    lds[t] = s;
    __syncthreads();
    for (int off = 128; off > 0; off >>= 1) {
        if (t < off) lds[t] += lds[t + off];
        __syncthreads();
    }
    if (t == 0) bsum[b] = lds[0];
}

__global__ __launch_bounds__(256) void k_btops(const int* bsum, int* boff, int* rowptr,
                                               int NB, int NN) {
    __shared__ int lds[256];
    int t = threadIdx.x;
    if (t < NB) lds[t] = bsum[t];
    __syncthreads();
    if (t == 0) {
        int run = 0;
        for (int i = 0; i < NB; i++) { int v = lds[i]; boff[i] = run; run += v; }
        rowptr[NN] = run;   // == E
    }
}

__global__ __launch_bounds__(256) void k_scan(const int* __restrict__ cnt,
                                              const int* __restrict__ boff,
                                              int* rowptr, int NN) {
    __shared__ int lds[2][256];
    int b = blockIdx.x, t = threadIdx.x;
    int base = b * 1024 + t * 4;
    int v[4]; int s = 0;
#pragma unroll
    for (int j = 0; j < 4; j++) { v[j] = (base + j < NN) ? cnt[base + j] : 0; s += v[j]; }
    lds[0][t] = s;
    __syncthreads();
    int cur = 0;
    for (int off = 1; off < 256; off <<= 1) {
        int val = lds[cur][t];
        if (t >= off) val += lds[cur][t - off];
        lds[cur ^ 1][t] = val;
        __syncthreads();
        cur ^= 1;
    }
    int excl = lds[cur][t] - s + boff[b];
#pragma unroll
    for (int j = 0; j < 4; j++) {
        if (base + j < NN) rowptr[base + j] = excl;
        excl += v[j];
    }
}

// ---------------- CSR fill — store-only, no atomics ----------------
__global__ __launch_bounds__(256) void k_fill(const int* __restrict__ src,
                                              const int* __restrict__ dst,
                                              const float* __restrict__ ew,
                                              const ushort* __restrict__ aux,
                                              const float* __restrict__ dinv,
                                              const int* __restrict__ rowptr,
                                              uint2* __restrict__ csr, int E) {
    int e = blockIdx.x * 256 + threadIdx.x;
    if (e < E) {
        int d = dst[e], s = src[e];
        float nrm = dinv[s] * ew[e] * dinv[d];
        csr[rowptr[d] + (int)aux[e]] = make_uint2((uint)s, __float_as_uint(nrm));
    }
}

// ---------------- graph node counts from sorted batch (binary search) --------
__global__ __launch_bounds__(64) void k_gcnt(const int* __restrict__ batch,
                                             int* __restrict__ gcnt, int NN, int G) {
    int g = threadIdx.x;
    if (g >= G) return;
    auto lb = [&](int v) {
        int lo = 0, hi = NN;
        while (lo < hi) { int mid = (lo + hi) >> 1; if (batch[mid] < v) lo = mid + 1; else hi = mid; }
        return lo;
    };
    gcnt[g] = lb(g + 1) - lb(g);
}

// ---------------- W[128][128] fp32 -> Wt[n][k] bf16 (transpose+cast) ---------
__global__ __launch_bounds__(256) void k_wt(const float* __restrict__ W,
                                            ushort* __restrict__ Wt) {
    int t = threadIdx.x;
    for (int i = t; i < FDIM * FDIM; i += 256) {
        int k = i >> 7, n = i & 127;
        Wt[n * FDIM + k] = f2bf(W[i]);
    }
}

// ---------------- bf16 MFMA GEMM: H[N,128] = X[N,128] @ Wt^T, fp8 out --------
__global__ __launch_bounds__(256) void k_gemm(const float* __restrict__ X,
                                              const ushort* __restrict__ Wt,
                                              uchar* __restrict__ H, int N) {
    int t = threadIdx.x;
    int wave = t >> 6, l = t & 63;
    int m = l & 15, kg = (l >> 4) * 8;
    int r0 = blockIdx.x * 64 + wave * 16;
    int row = r0 + m;
    short8v a[4];
    if (row < N) {
#pragma unroll
        for (int ks = 0; ks < 4; ks++) {
            const float* xp = X + (size_t)row * FDIM + ks * 32 + kg;
            float4 f0 = *(const float4*)xp;
            float4 f1 = *(const float4*)(xp + 4);
            short8v av;
            av[0] = (short)f2bf(f0.x); av[1] = (short)f2bf(f0.y);
            av[2] = (short)f2bf(f0.z); av[3] = (short)f2bf(f0.w);
            av[4] = (short)f2bf(f1.x); av[5] = (short)f2bf(f1.y);
            av[6] = (short)f2bf(f1.z); av[7] = (short)f2bf(f1.w);
            a[ks] = av;
        }
    } else {
#pragma unroll
        for (int ks = 0; ks < 4; ks++) a[ks] = (short8v)0;
    }
    int orow = r0 + (l >> 4) * 4;
#pragma unroll
    for (int c = 0; c < 8; c++) {
        f32x4 acc = {0.f, 0.f, 0.f, 0.f};
#pragma unroll
        for (int ks = 0; ks < 4; ks++) {
            short8v b = *(const short8v*)(Wt + (size_t)(c * 16 + m) * FDIM + ks * 32 + kg);
            acc = __builtin_amdgcn_mfma_f32_16x16x32_bf16(a[ks], b, acc, 0, 0, 0);
        }
#pragma unroll
        for (int j = 0; j < 4; j++)
            if (orow + j < N)
                H[(size_t)(orow + j) * FDIM + c * 16 + m] = fp8_enc1(acc[j]);
    }
}

// ---------------- gather aggregation v5: software-pipelined ------------------
// 8 edge-slots/wave (sg = l>>3), 8 lanes/slot x uint4 = full 128B fp8 row.
// csr descriptors 3 batches ahead, H rows 1 batch ahead, static rotation.
// RELU: bias+relu, store fp8 Z.  POOL: no bias, pool into psum[batch[n]].
template <int RELU, int POOL>
__global__ __launch_bounds__(256) void k_agg(const uchar* __restrict__ H,
                                             const int* __restrict__ rowptr,
                                             const uint2* __restrict__ csr,
                                             const float* __restrict__ dinv,
                                             const float* __restrict__ bias,
                                             uchar* __restrict__ Z,
                                             const int* __restrict__ batch,
                                             float* __restrict__ psum, int NN) {
    __shared__ float pool[FDIM];
    int t = threadIdx.x;
    int wave = t >> 6, l = t & 63;
    int sg = l >> 3, li = l & 7;
    int f0 = li * 16;
    int gmin = 0;
    if (POOL) {
        if (t < FDIM) pool[t] = 0.0f;
        gmin = batch[blockIdx.x * 16];
        __syncthreads();
    }

    for (int it = 0; it < 4; ++it) {
        int n = blockIdx.x * 16 + wave * 4 + it;
        if (n >= NN) continue;
        int rs = rowptr[n], re = rowptr[n + 1];
        float acc[16];
        if (sg == 0) {
            uint4 hv = *(const uint4*)(H + (size_t)n * FDIM + f0);
            float di = dinv[n];
            float sw = di * di;
            float hf[16];
            fp8x16_dec(hv, hf);
#pragma unroll
            for (int j = 0; j < 16; j++) acc[j] = sw * hf[j];
        } else {
#pragma unroll
            for (int j = 0; j < 16; j++) acc[j] = 0.0f;
        }
        if (rs < re) {
            int last = re - 1;
            uint2 pd0 = csr[min(rs + sg, last)];
            uint2 pd1 = csr[min(rs + 8 + sg, last)];
            uint2 pd2 = csr[min(rs + 16 + sg, last)];
            uint4 hv0 = *(const uint4*)(H + (size_t)pd0.x * FDIM + f0);
            float w0 = (rs + sg < re) ? __uint_as_float(pd0.y) : 0.0f;
            for (int e = rs; e < re; e += 8) {
                uint2 pd3 = csr[min(e + 24 + sg, last)];
                uint4 hv1 = hv0;
                float w1 = 0.0f;
                if (e + 8 < re) {                       // wave-uniform branch
                    hv1 = *(const uint4*)(H + (size_t)pd1.x * FDIM + f0);
                    w1 = (e + 8 + sg < re) ? __uint_as_float(pd1.y) : 0.0f;
                }
                float g[16];
                fp8x16_dec(hv0, g);
#pragma unroll
                for (int j = 0; j < 16; j++) acc[j] = fmaf(w0, g[j], acc[j]);
                pd0 = pd1; pd1 = pd2; pd2 = pd3; hv0 = hv1; w0 = w1;
            }
        }
#pragma unroll
        for (int j = 0; j < 16; j++) {
            acc[j] += __shfl_xor(acc[j], 8);
            acc[j] += __shfl_xor(acc[j], 16);
            acc[j] += __shfl_xor(acc[j], 32);
        }
        if (sg == 0) {
            if (POOL) {
                int g = batch[n];
                if (g == gmin) {
#pragma unroll
                    for (int j = 0; j < 16; j++) atomicAdd(&pool[f0 + j], acc[j]);
                } else {
#pragma unroll
                    for (int j = 0; j < 16; j++) atomicAdd(&psum[g * FDIM + f0 + j], acc[j]);
                }
            } else {
#pragma unroll
                for (int j = 0; j < 16; j++) acc[j] = acc[j] + bias[f0 + j];
                if (RELU) {
#pragma unroll
                    for (int j = 0; j < 16; j++) acc[j] = fmaxf(acc[j], 0.0f);
                }
                *(uint4*)(Z + (size_t)n * FDIM + f0) = fp8x16_enc(acc);
            }
        }
    }
    if (POOL) {
        __syncthreads();
        if (t < FDIM) atomicAdd(&psum[gmin * FDIM + t], pool[t]);
    }
}

// ---------------- mean + W2 + b2 + Wfc + bfc (two tiny GEMMs fused) ----------
__global__ __launch_bounds__(128) void k_fc2(const float* __restrict__ psum,
                                             const int* __restrict__ gcnt,
                                             const float* __restrict__ W2,
                                             const float* __restrict__ b2,
                                             const float* __restrict__ Wfc,
                                             const float* __restrict__ bfc,
                                             float* __restrict__ out) {
    __shared__ float p[FDIM], t1[FDIM];
    int g = blockIdx.x, f = threadIdx.x;
    float c = (float)max(gcnt[g], 1);
    p[f] = psum[g * FDIM + f] / c;
    __syncthreads();
    float acc = b2[f];
#pragma unroll 8
    for (int k = 0; k < FDIM; k++) acc = fmaf(p[k], W2[k * FDIM + f], acc);
    t1[f] = acc;
    __syncthreads();
    float acc2 = bfc[f];
#pragma unroll 8
    for (int k = 0; k < FDIM; k++) acc2 = fmaf(t1[k], Wfc[k * FDIM + f], acc2);
    out[g * FDIM + f] = acc2;
}

extern "C" void kernel_launch(void* const* d_in, const int* in_sizes, int n_in,
                              void* d_out, int out_size, void* d_ws, size_t ws_size,
                              hipStream_t stream) {
    const float* x    = (const float*)d_in[0];
    const int*   ei   = (const int*)d_in[1];
    const float* ew   = (const float*)d_in[2];
    const int*   batch= (const int*)d_in[3];
    const float* W1   = (const float*)d_in[4];
    const float* b1   = (const float*)d_in[5];
    const float* W2   = (const float*)d_in[6];
    const float* b2   = (const float*)d_in[7];
    const float* Wfc  = (const float*)d_in[8];
    const float* bfc  = (const float*)d_in[9];
    float* out = (float*)d_out;

    int E  = in_sizes[2];       // 1,600,000
    int NN = in_sizes[3];       // 100,000
    int G  = out_size / FDIM;   // 64

    const int* src = ei;
    const int* dst = ei + E;

    char* ws = (char*)d_ws;
    size_t off = 0;
    auto alloc = [&](size_t bytes) -> void* {
        void* p = ws + off;
        off = (off + bytes + 255) & ~(size_t)255;
        return p;
    };
    unsigned long long* packed = (unsigned long long*)alloc((size_t)NN * 8);
    ushort* aux    = (ushort*)alloc((size_t)E * 2);
    int*   cnt     = (int*)alloc((size_t)NN * 4);
    float* dinv    = (float*)alloc((size_t)NN * 4);
    int*   rowptr  = (int*)alloc((size_t)(NN + 1) * 4);
    int*   bsumA   = (int*)alloc(256 * 4);
    int*   boffA   = (int*)alloc(256 * 4);
    uint2* csr     = (uint2*)alloc((size_t)E * 8);
    float* psum    = (float*)alloc((size_t)G * FDIM * 4);
    int*   gcnt    = (int*)alloc((size_t)G * 4);
    uchar* Bh      = (uchar*)alloc((size_t)NN * FDIM);      // h1 fp8
    uchar* Bz      = (uchar*)alloc((size_t)NN * FDIM);      // z1 fp8
    ushort* Wt1    = (ushort*)alloc((size_t)FDIM * FDIM * 2);
    (void)ws_size; (void)n_in;

    int nbN = (NN + 255) / 256;
    int nbE = (E + 255) / 256;
    int NB  = (NN + 1023) / 1024;   // 98

    k_init<<<nbN, 256, 0, stream>>>(packed, psum, NN, G * FDIM);
    k_hist<<<nbE, 256, 0, stream>>>(dst, ew, packed, aux, E);
    k_merge<<<nbN, 256, 0, stream>>>(packed, cnt, dinv, NN);
    k_bsum<<<NB, 256, 0, stream>>>(cnt, bsumA, NN);
    k_btops<<<1, 256, 0, stream>>>(bsumA, boffA, rowptr, NB, NN);
    k_scan<<<NB, 256, 0, stream>>>(cnt, boffA, rowptr, NN);
    k_fill<<<nbE, 256, 0, stream>>>(src, dst, ew, aux, dinv, rowptr, csr, E);
    k_gcnt<<<1, 64, 0, stream>>>(batch, gcnt, NN, G);
    k_wt<<<1, 256, 0, stream>>>(W1, Wt1);

    int nbG = (NN + 63) / 64;
    int nbA = (NN + 15) / 16;
    // layer 1: h1 = x@W1 ; z1 = relu(Agg(h1)+b1)
    k_gemm<<<nbG, 256, 0, stream>>>(x, Wt1, Bh, NN);
    k_agg<1, 0><<<nbA, 256, 0, stream>>>(Bh, rowptr, csr, dinv, b1, Bz,
                                         batch, psum, NN);
    // layer 2 pooled: psum[g] = sum_{d in g} (A_hat z1)[d]  (same CSR)
    k_agg<0, 1><<<nbA, 256, 0, stream>>>(Bz, rowptr, csr, dinv, nullptr, nullptr,
                                         batch, psum, NN);
    // out = ((psum/cnt)@W2 + b2)@Wfc + bfc
    k_fc2<<<G, 128, 0, stream>>>(psum, gcnt, W2, b2, Wfc, bfc, out);
}

// Round 14
// 335.791 us; speedup vs baseline: 1.1238x; 1.1238x over previous
//
#include <hip/hip_runtime.h>
#include <hip/hip_fp16.h>
#include <hip/hip_fp8.h>

// GCN: z1 = relu(Agg(x@W1)+b1); out = ((P·Â·z1)@W2 + b2)@Wfc + bfc
//   (pooling commuted before W2; P·Â·z1 pooled row-wise over dst).
// ONE CSR (by dst) serves both layers. Intermediates h1/z1 FP8 e4m3 (HW
// cvt_pk). Round-13 lesson: register-rotation pipeline SERIALIZED the gather
// (one load in flight) — reverted. This round: v3 layout (4 slots x 16 lanes
// x uint2) with an EXPLICIT 16-edge straight-line batch (4 descriptor loads,
// then 4 independent row loads, then consume) — the round-2-proven pattern.
// Build: 1 atomic/edge (counting sort via atomic return; ~67us floor).

constexpr int FDIM = 128;

typedef __attribute__((ext_vector_type(8))) short short8v;
typedef __attribute__((ext_vector_type(4))) float f32x4;
typedef __attribute__((ext_vector_type(2))) float f32x2;

__device__ __forceinline__ ushort f2bf(float f) {
    uint u = __float_as_uint(f);
    return (ushort)((u + 0x7fffu + ((u >> 16) & 1u)) >> 16);
}

#if __has_builtin(__builtin_amdgcn_cvt_pk_f32_fp8) && __has_builtin(__builtin_amdgcn_cvt_pk_fp8_f32)
#define FP8_HW 1
#else
#define FP8_HW 0
#endif

__device__ __forceinline__ void fp8x8_dec(uint2 v, float* f) {
#if FP8_HW
    f32x2 a = __builtin_amdgcn_cvt_pk_f32_fp8(v.x, false);
    f32x2 b = __builtin_amdgcn_cvt_pk_f32_fp8(v.x, true);
    f32x2 c = __builtin_amdgcn_cvt_pk_f32_fp8(v.y, false);
    f32x2 d = __builtin_amdgcn_cvt_pk_f32_fp8(v.y, true);
    f[0] = a[0]; f[1] = a[1]; f[2] = b[0]; f[3] = b[1];
    f[4] = c[0]; f[5] = c[1]; f[6] = d[0]; f[7] = d[1];
#else
    __half2_raw h;
    h = __hip_cvt_fp8x2_to_halfraw2((__hip_fp8x2_storage_t)(v.x & 0xffffu), __HIP_E4M3);
    float2 a = __half22float2(*(__half2*)&h);
    f[0] = a.x; f[1] = a.y;
    h = __hip_cvt_fp8x2_to_halfraw2((__hip_fp8x2_storage_t)(v.x >> 16), __HIP_E4M3);
    a = __half22float2(*(__half2*)&h);
    f[2] = a.x; f[3] = a.y;
    h = __hip_cvt_fp8x2_to_halfraw2((__hip_fp8x2_storage_t)(v.y & 0xffffu), __HIP_E4M3);
    a = __half22float2(*(__half2*)&h);
    f[4] = a.x; f[5] = a.y;
    h = __hip_cvt_fp8x2_to_halfraw2((__hip_fp8x2_storage_t)(v.y >> 16), __HIP_E4M3);
    a = __half22float2(*(__half2*)&h);
    f[6] = a.x; f[7] = a.y;
#endif
}
__device__ __forceinline__ uint2 fp8x8_enc(const float* f) {
#if FP8_HW
    int lo = 0, hi = 0;
    lo = __builtin_amdgcn_cvt_pk_fp8_f32(f[0], f[1], lo, false);
    lo = __builtin_amdgcn_cvt_pk_fp8_f32(f[2], f[3], lo, true);
    hi = __builtin_amdgcn_cvt_pk_fp8_f32(f[4], f[5], hi, false);
    hi = __builtin_amdgcn_cvt_pk_fp8_f32(f[6], f[7], hi, true);
    return make_uint2((uint)lo, (uint)hi);
#else
    uint p0 = __hip_cvt_float2_to_fp8x2(make_float2(f[0], f[1]), __HIP_SATFINITE, __HIP_E4M3);
    uint p1 = __hip_cvt_float2_to_fp8x2(make_float2(f[2], f[3]), __HIP_SATFINITE, __HIP_E4M3);
    uint p2 = __hip_cvt_float2_to_fp8x2(make_float2(f[4], f[5]), __HIP_SATFINITE, __HIP_E4M3);
    uint p3 = __hip_cvt_float2_to_fp8x2(make_float2(f[6], f[7]), __HIP_SATFINITE, __HIP_E4M3);
    return make_uint2(p0 | (p1 << 16), p2 | (p3 << 16));
#endif
}
__device__ __forceinline__ uchar fp8_enc1(float f) {
#if FP8_HW
    return (uchar)((uint)__builtin_amdgcn_cvt_pk_fp8_f32(f, f, 0, false) & 0xffu);
#else
    return (uchar)__hip_cvt_float_to_fp8(f, __HIP_SATFINITE, __HIP_E4M3);
#endif
}

// ---------------- init: zero histogram + psum ----------------
__global__ __launch_bounds__(256) void k_init(unsigned long long* packed,
                                              float* psum, int NN, int PS) {
    int i = blockIdx.x * 256 + threadIdx.x;
    if (i < NN) packed[i] = 0ULL;
    if (i < PS) psum[i] = 0.0f;
}

// ---------------- histogram + CSR position (single atomic/edge) --------------
__global__ __launch_bounds__(256) void k_hist(const int* __restrict__ dst,
                                              const float* __restrict__ ew,
                                              unsigned long long* __restrict__ packed,
                                              ushort* __restrict__ aux, int E) {
    int e = blockIdx.x * 256 + threadIdx.x;
    if (e < E) {
        int d = dst[e];
        uint fix = __float2uint_rn(ew[e] * 16777216.0f);   // 2^24 fixed point
        unsigned long long old =
            atomicAdd(&packed[d], (1ULL << 32) | (unsigned long long)fix);
        aux[e] = (ushort)(old >> 32);                      // slot in dst bucket
    }
}

// ---------------- merge: packed -> cnt, dinv ----------------
__global__ __launch_bounds__(256) void k_merge(const unsigned long long* __restrict__ packed,
                                               int* __restrict__ cnt,
                                               float* __restrict__ dinv, int NN) {
    int n = blockIdx.x * 256 + threadIdx.x;
    if (n >= NN) return;
    unsigned long long v = packed[n];
    cnt[n] = (int)(v >> 32);
    float deg = 1.0f + (float)(v & 0xffffffffULL) * 5.9604644775390625e-8f;  // 2^-24
    dinv[n] = rsqrtf(deg);
}

// ---------------- exclusive scan (3-kernel, chunk=1024) ----------------
__global__ __launch_bounds__(256) void k_bsum(const int* __restrict__ cnt, int* bsum, int NN) {
    __shared__ int lds[256];
    int b = blockIdx.x, t = threadIdx.x;
    int base = b * 1024;
    int s = 0;
#pragma unroll
    for (int j = 0; j < 4; j++) {
        int i = base + j * 256 + t;
        if (i < NN) s += cnt[i];
    }
    lds[t] = s;
    __syncthreads();
    for (int off = 128; off > 0; off >>= 1) {
        if (t < off) lds[t] += lds[t + off];
        __syncthreads();
    }
    if (t == 0) bsum[b] = lds[0];
}

__global__ __launch_bounds__(256) void k_btops(const int* bsum, int* boff, int* rowptr,
                                               int NB, int NN) {
    __shared__ int lds[256];
    int t = threadIdx.x;
    if (t < NB) lds[t] = bsum[t];
    __syncthreads();
    if (t == 0) {
        int run = 0;
        for (int i = 0; i < NB; i++) { int v = lds[i]; boff[i] = run; run += v; }
        rowptr[NN] = run;   // == E
    }
}

__global__ __launch_bounds__(256) void k_scan(const int* __restrict__ cnt,
                                              const int* __restrict__ boff,
                                              int* rowptr, int NN) {
    __shared__ int lds[2][256];
    int b = blockIdx.x, t = threadIdx.x;
    int base = b * 1024 + t * 4;
    int v[4]; int s = 0;
#pragma unroll
    for (int j = 0; j < 4; j++) { v[j] = (base + j < NN) ? cnt[base + j] : 0; s += v[j]; }
    lds[0][t] = s;
    __syncthreads();
    int cur = 0;
    for (int off = 1; off < 256; off <<= 1) {
        int val = lds[cur][t];
        if (t >= off) val += lds[cur][t - off];
        lds[cur ^ 1][t] = val;
        __syncthreads();
        cur ^= 1;
    }
    int excl = lds[cur][t] - s + boff[b];
#pragma unroll
    for (int j = 0; j < 4; j++) {
        if (base + j < NN) rowptr[base + j] = excl;
        excl += v[j];
    }
}

// ---------------- CSR fill — store-only, no atomics ----------------
__global__ __launch_bounds__(256) void k_fill(const int* __restrict__ src,
                                              const int* __restrict__ dst,
                                              const float* __restrict__ ew,
                                              const ushort* __restrict__ aux,
                                              const float* __restrict__ dinv,
                                              const int* __restrict__ rowptr,
                                              uint2* __restrict__ csr, int E) {
    int e = blockIdx.x * 256 + threadIdx.x;
    if (e < E) {
        int d = dst[e], s = src[e];
        float nrm = dinv[s] * ew[e] * dinv[d];
        csr[rowptr[d] + (int)aux[e]] = make_uint2((uint)s, __float_as_uint(nrm));
    }
}

// ---------------- graph node counts from sorted batch (binary search) --------
__global__ __launch_bounds__(64) void k_gcnt(const int* __restrict__ batch,
                                             int* __restrict__ gcnt, int NN, int G) {
    int g = threadIdx.x;
    if (g >= G) return;
    auto lb = [&](int v) {
        int lo = 0, hi = NN;
        while (lo < hi) { int mid = (lo + hi) >> 1; if (batch[mid] < v) lo = mid + 1; else hi = mid; }
        return lo;
    };
    gcnt[g] = lb(g + 1) - lb(g);
}

// ---------------- W[128][128] fp32 -> Wt[n][k] bf16 (transpose+cast) ---------
__global__ __launch_bounds__(256) void k_wt(const float* __restrict__ W,
                                            ushort* __restrict__ Wt) {
    int t = threadIdx.x;
    for (int i = t; i < FDIM * FDIM; i += 256) {
        int k = i >> 7, n = i & 127;
        Wt[n * FDIM + k] = f2bf(W[i]);
    }
}

// ---------------- bf16 MFMA GEMM: H[N,128] = X[N,128] @ Wt^T, fp8 out --------
__global__ __launch_bounds__(256) void k_gemm(const float* __restrict__ X,
                                              const ushort* __restrict__ Wt,
                                              uchar* __restrict__ H, int N) {
    int t = threadIdx.x;
    int wave = t >> 6, l = t & 63;
    int m = l & 15, kg = (l >> 4) * 8;
    int r0 = blockIdx.x * 64 + wave * 16;
    int row = r0 + m;
    short8v a[4];
    if (row < N) {
#pragma unroll
        for (int ks = 0; ks < 4; ks++) {
            const float* xp = X + (size_t)row * FDIM + ks * 32 + kg;
            float4 f0 = *(const float4*)xp;
            float4 f1 = *(const float4*)(xp + 4);
            short8v av;
            av[0] = (short)f2bf(f0.x); av[1] = (short)f2bf(f0.y);
            av[2] = (short)f2bf(f0.z); av[3] = (short)f2bf(f0.w);
            av[4] = (short)f2bf(f1.x); av[5] = (short)f2bf(f1.y);
            av[6] = (short)f2bf(f1.z); av[7] = (short)f2bf(f1.w);
            a[ks] = av;
        }
    } else {
#pragma unroll
        for (int ks = 0; ks < 4; ks++) a[ks] = (short8v)0;
    }
    int orow = r0 + (l >> 4) * 4;
#pragma unroll
    for (int c = 0; c < 8; c++) {
        f32x4 acc = {0.f, 0.f, 0.f, 0.f};
#pragma unroll
        for (int ks = 0; ks < 4; ks++) {
            short8v b = *(const short8v*)(Wt + (size_t)(c * 16 + m) * FDIM + ks * 32 + kg);
            acc = __builtin_amdgcn_mfma_f32_16x16x32_bf16(a[ks], b, acc, 0, 0, 0);
        }
#pragma unroll
        for (int j = 0; j < 4; j++)
            if (orow + j < N)
                H[(size_t)(orow + j) * FDIM + c * 16 + m] = fp8_enc1(acc[j]);
    }
}

// ---------------- gather aggregation v6: explicit 16-edge batch --------------
// 4 edge-slots (eg = l>>4), 16 lanes x uint2 = 128B fp8 row per slot.
// Per batch: 4 descriptor loads, then 4 INDEPENDENT row loads back-to-back
// (4 granules in flight/wave), then consume. No cross-iteration rotation.
// RELU: bias+relu, store fp8 Z.  POOL: no bias, pool into psum[batch[n]].
template <int RELU, int POOL>
__global__ __launch_bounds__(256) void k_agg(const uchar* __restrict__ H,
                                             const int* __restrict__ rowptr,
                                             const uint2* __restrict__ csr,
                                             const float* __restrict__ dinv,
                                             const float* __restrict__ bias,
                                             uchar* __restrict__ Z,
                                             const int* __restrict__ batch,
                                             float* __restrict__ psum, int NN) {
    __shared__ float pool[FDIM];
    int t = threadIdx.x;
    int wave = t >> 6, l = t & 63;
    int eg = l >> 4, li = l & 15;
    int f0 = li * 8;
    int gmin = 0;
    if (POOL) {
        if (t < FDIM) pool[t] = 0.0f;
        gmin = batch[blockIdx.x * 16];
        __syncthreads();
    }

    for (int it = 0; it < 4; ++it) {
        int n = blockIdx.x * 16 + wave * 4 + it;
        if (n >= NN) continue;
        float acc[8];
        if (eg == 0) {
            float di = dinv[n];
            float sw = di * di;
            uint2 hv = *(const uint2*)(H + (size_t)n * FDIM + f0);
            float hf[8];
            fp8x8_dec(hv, hf);
#pragma unroll
            for (int j = 0; j < 8; j++) acc[j] = sw * hf[j];
        } else {
#pragma unroll
            for (int j = 0; j < 8; j++) acc[j] = 0.0f;
        }
        int rs = rowptr[n], re = rowptr[n + 1];
        int last = re - 1;
        for (int e = rs; e < re; e += 16) {
            uint2 p[4];
#pragma unroll
            for (int b = 0; b < 4; b++)
                p[b] = csr[min(e + b * 4 + eg, last)];
            uint2 v[4];
#pragma unroll
            for (int b = 0; b < 4; b++)
                v[b] = *(const uint2*)(H + (size_t)p[b].x * FDIM + f0);
#pragma unroll
            for (int b = 0; b < 4; b++) {
                float w = (e + b * 4 + eg < re) ? __uint_as_float(p[b].y) : 0.0f;
                float g[8];
                fp8x8_dec(v[b], g);
#pragma unroll
                for (int j = 0; j < 8; j++) acc[j] = fmaf(w, g[j], acc[j]);
            }
        }
#pragma unroll
        for (int j = 0; j < 8; j++) {
            acc[j] += __shfl_xor(acc[j], 16);
            acc[j] += __shfl_xor(acc[j], 32);
        }
        if (eg == 0) {
            if (POOL) {
                int g = batch[n];
                if (g == gmin) {
#pragma unroll
                    for (int j = 0; j < 8; j++) atomicAdd(&pool[f0 + j], acc[j]);
                } else {
#pragma unroll
                    for (int j = 0; j < 8; j++) atomicAdd(&psum[g * FDIM + f0 + j], acc[j]);
                }
            } else {
#pragma unroll
                for (int j = 0; j < 8; j++) acc[j] = acc[j] + bias[f0 + j];
                if (RELU) {
#pragma unroll
                    for (int j = 0; j < 8; j++) acc[j] = fmaxf(acc[j], 0.0f);
                }
                *(uint2*)(Z + (size_t)n * FDIM + f0) = fp8x8_enc(acc);
            }
        }
    }
    if (POOL) {
        __syncthreads();
        if (t < FDIM) atomicAdd(&psum[gmin * FDIM + t], pool[t]);
    }
}

// ---------------- mean + W2 + b2 + Wfc + bfc (two tiny GEMMs fused) ----------
__global__ __launch_bounds__(128) void k_fc2(const float* __restrict__ psum,
                                             const int* __restrict__ gcnt,
                                             const float* __restrict__ W2,
                                             const float* __restrict__ b2,
                                             const float* __restrict__ Wfc,
                                             const float* __restrict__ bfc,
                                             float* __restrict__ out) {
    __shared__ float p[FDIM], t1[FDIM];
    int g = blockIdx.x, f = threadIdx.x;
    float c = (float)max(gcnt[g], 1);
    p[f] = psum[g * FDIM + f] / c;
    __syncthreads();
    float acc = b2[f];
#pragma unroll 8
    for (int k = 0; k < FDIM; k++) acc = fmaf(p[k], W2[k * FDIM + f], acc);
    t1[f] = acc;
    __syncthreads();
    float acc2 = bfc[f];
#pragma unroll 8
    for (int k = 0; k < FDIM; k++) acc2 = fmaf(t1[k], Wfc[k * FDIM + f], acc2);
    out[g * FDIM + f] = acc2;
}

extern "C" void kernel_launch(void* const* d_in, const int* in_sizes, int n_in,
                              void* d_out, int out_size, void* d_ws, size_t ws_size,
                              hipStream_t stream) {
    const float* x    = (const float*)d_in[0];
    const int*   ei   = (const int*)d_in[1];
    const float* ew   = (const float*)d_in[2];
    const int*   batch= (const int*)d_in[3];
    const float* W1   = (const float*)d_in[4];
    const float* b1   = (const float*)d_in[5];
    const float* W2   = (const float*)d_in[6];
    const float* b2   = (const float*)d_in[7];
    const float* Wfc  = (const float*)d_in[8];
    const float* bfc  = (const float*)d_in[9];
    float* out = (float*)d_out;

    int E  = in_sizes[2];       // 1,600,000
    int NN = in_sizes[3];       // 100,000
    int G  = out_size / FDIM;   // 64

    const int* src = ei;
    const int* dst = ei + E;

    char* ws = (char*)d_ws;
    size_t off = 0;
    auto alloc = [&](size_t bytes) -> void* {
        void* p = ws + off;
        off = (off + bytes + 255) & ~(size_t)255;
        return p;
    };
    unsigned long long* packed = (unsigned long long*)alloc((size_t)NN * 8);
    ushort* aux    = (ushort*)alloc((size_t)E * 2);
    int*   cnt     = (int*)alloc((size_t)NN * 4);
    float* dinv    = (float*)alloc((size_t)NN * 4);
    int*   rowptr  = (int*)alloc((size_t)(NN + 1) * 4);
    int*   bsumA   = (int*)alloc(256 * 4);
    int*   boffA   = (int*)alloc(256 * 4);
    uint2* csr     = (uint2*)alloc((size_t)E * 8);
    float* psum    = (float*)alloc((size_t)G * FDIM * 4);
    int*   gcnt    = (int*)alloc((size_t)G * 4);
    uchar* Bh      = (uchar*)alloc((size_t)NN * FDIM);      // h1 fp8
    uchar* Bz      = (uchar*)alloc((size_t)NN * FDIM);      // z1 fp8
    ushort* Wt1    = (ushort*)alloc((size_t)FDIM * FDIM * 2);
    (void)ws_size; (void)n_in;

    int nbN = (NN + 255) / 256;
    int nbE = (E + 255) / 256;
    int NB  = (NN + 1023) / 1024;   // 98

    k_init<<<nbN, 256, 0, stream>>>(packed, psum, NN, G * FDIM);
    k_hist<<<nbE, 256, 0, stream>>>(dst, ew, packed, aux, E);
    k_merge<<<nbN, 256, 0, stream>>>(packed, cnt, dinv, NN);
    k_bsum<<<NB, 256, 0, stream>>>(cnt, bsumA, NN);
    k_btops<<<1, 256, 0, stream>>>(bsumA, boffA, rowptr, NB, NN);
    k_scan<<<NB, 256, 0, stream>>>(cnt, boffA, rowptr, NN);
    k_fill<<<nbE, 256, 0, stream>>>(src, dst, ew, aux, dinv, rowptr, csr, E);
    k_gcnt<<<1, 64, 0, stream>>>(batch, gcnt, NN, G);
    k_wt<<<1, 256, 0, stream>>>(W1, Wt1);

    int nbG = (NN + 63) / 64;
    int nbA = (NN + 15) / 16;
    // layer 1: h1 = x@W1 ; z1 = relu(Agg(h1)+b1)
    k_gemm<<<nbG, 256, 0, stream>>>(x, Wt1, Bh, NN);
    k_agg<1, 0><<<nbA, 256, 0, stream>>>(Bh, rowptr, csr, dinv, b1, Bz,
                                         batch, psum, NN);
    // layer 2 pooled: psum[g] = sum_{d in g} (A_hat z1)[d]  (same CSR)
    k_agg<0, 1><<<nbA, 256, 0, stream>>>(Bz, rowptr, csr, dinv, nullptr, nullptr,
                                         batch, psum, NN);
    // out = ((psum/cnt)@W2 + b2)@Wfc + bfc
    k_fc2<<<G, 128, 0, stream>>>(psum, gcnt, W2, b2, Wfc, bfc, out);
}